// Round 6
// baseline (330.542 us; speedup 1.0000x reference)
//
#include <hip/hip_runtime.h>
#include <hip/hip_bf16.h>
#include <hip/hip_fp16.h>

#define D 50
#define PADH 64                     // fp16 row stride: 128 B = 2 aligned 64B lines
#define GLAM 0.05555555555555555f   // gamma * lambda = (1/(2*0.9)) * 0.1
#define SCAN_B 1024
#define FIXS 8388608.0f             // 2^23 fixed-point scale (degree sums)
#define INV_FIXS (1.0f / 8388608.0f)
#define WSC 32768.0f                // 2^15 weight scale for u32 CSR records
#define INV_WSC (1.0f / 32768.0f)
#define EPB 4096                    // edges per binning block
#define EPT 8                       // edges per thread in k_b2 (EPB/B2T)
#define B2T 512                     // threads for b1/b2
#define BSH 8                       // 256-node buckets (391 @100k -> >1 block/CU)
#define BMSK 255u
#define BKT 256                     // bucket size = threads for srcdeg/dstfill
#define MAXB 512                    // max buckets (supports n <= 131072)
#define MAXRUN 6144                 // pe staging capacity in k_dstfill (24 KB)
#define NXCD 8

typedef unsigned long long u64;

// ---- pass 1: per-block bucket histograms (dst+src), FUSED with feat->fp16 pad ----
__global__ void k_b1p(const int* __restrict__ src, const int* __restrict__ dst,
                      int* __restrict__ mat, const float* __restrict__ feat,
                      __half* __restrict__ xp, int e, int nblk, int nbuk, int n) {
    if ((int)blockIdx.x < nblk) {
        __shared__ unsigned hd[MAXB], hs[MAXB];
        for (int j = threadIdx.x; j < nbuk; j += blockDim.x) { hd[j] = 0; hs[j] = 0; }
        __syncthreads();
        int base = blockIdx.x * EPB;
        int end = base + EPB; if (end > e) end = e;
        for (int i = base + threadIdx.x; i < end; i += blockDim.x) {
            int t = __builtin_nontemporal_load(dst + i);
            int s = __builtin_nontemporal_load(src + i);
            atomicAdd(&hd[t >> BSH], 1u);
            atomicAdd(&hs[s >> BSH], 1u);
        }
        __syncthreads();
        for (int j = threadIdx.x; j < nbuk; j += blockDim.x) {
            mat[j * nblk + blockIdx.x] = (int)hd[j];
            mat[(nbuk + j) * nblk + blockIdx.x] = (int)hs[j];
        }
    } else {
        int i = ((int)blockIdx.x - nblk) * (int)blockDim.x + (int)threadIdx.x;
        if (i < n * PADH) {
            int node = i >> 6, col = i & 63;
            xp[i] = (col < D) ? __float2half_rn(feat[node * D + col]) : __half(0.0f);
        }
    }
}

// ---- 3-kernel exclusive scan (for the bucket-count matrix) ----
__global__ void k_scan1(const int* __restrict__ cnt, int* __restrict__ out,
                        int* __restrict__ bsum, int n) {
    __shared__ int s[SCAN_B];
    int i = blockIdx.x * SCAN_B + threadIdx.x;
    int v = (i < n) ? cnt[i] : 0;
    s[threadIdx.x] = v; __syncthreads();
    for (int off = 1; off < SCAN_B; off <<= 1) {
        int t = (threadIdx.x >= (unsigned)off) ? s[threadIdx.x - off] : 0;
        __syncthreads();
        s[threadIdx.x] += t; __syncthreads();
    }
    if (i < n) out[i] = s[threadIdx.x] - v;             // exclusive
    if (threadIdx.x == SCAN_B - 1) bsum[blockIdx.x] = s[threadIdx.x];
}

__global__ void k_scan2(int* __restrict__ bsum, int nb) {
    __shared__ int s[SCAN_B];
    int v = (threadIdx.x < (unsigned)nb) ? bsum[threadIdx.x] : 0;
    s[threadIdx.x] = v; __syncthreads();
    for (int off = 1; off < SCAN_B; off <<= 1) {
        int t = (threadIdx.x >= (unsigned)off) ? s[threadIdx.x - off] : 0;
        __syncthreads();
        s[threadIdx.x] += t; __syncthreads();
    }
    if (threadIdx.x < (unsigned)nb) bsum[threadIdx.x] = s[threadIdx.x] - v;  // exclusive
}

__global__ void k_scan3(int* __restrict__ out, const int* __restrict__ bsum, int n) {
    int i = blockIdx.x * SCAN_B + threadIdx.x;
    if (i < n) out[i] += bsum[blockIdx.x];
}

// ---- bijective chunked XCD swizzle (m204): phys block -> work block ----
__device__ __forceinline__ int xcd_swz(int p, int nwg) {
    int q = nwg / NXCD, r = nwg % NXCD;
    int xcd = p % NXCD, idx = p / NXCD;
    return (xcd < r ? xcd * (q + 1) : r * (q + 1) + (xcd - r) * q) + idx;
}

// ---- pass 2: LDS counting sort per block -> coalesced binned writes ----
// Edges held in registers (no HBM re-read). LDS ~76 KB -> 2 blocks/CU.
// Ordered placement (matrix scan) + XCD swizzle keeps adjacent chunks on
// the same XCD L2 so boundary partial lines merge.
__global__ __launch_bounds__(B2T, 4) void k_b2(
                     const float* __restrict__ ew, const int* __restrict__ src,
                     const int* __restrict__ dst, const int* __restrict__ msc,
                     u64* __restrict__ bind, unsigned* __restrict__ bins,
                     int e, int nblk, int nbuk) {
    __shared__ unsigned cd[MAXB], cs[MAXB];      // counts -> cursors
    __shared__ unsigned ld[MAXB], ls[MAXB];      // local exclusive starts
    __shared__ int gbd[MAXB], gbs[MAXB];         // global bases per bucket
    __shared__ u64 sd[EPB];                      // 32 KB dst-records staging
    __shared__ unsigned ss[EPB];                 // 16 KB src-records staging
    __shared__ unsigned short bdd[EPB], bds[EPB];// bucket id per staged slot (16 KB)
    int tid = threadIdx.x;
    int wb = xcd_swz((int)blockIdx.x, nblk);
    if (tid < MAXB) { cd[tid] = 0; cs[tid] = 0; }
    __syncthreads();
    int base = wb * EPB;
    int end = base + EPB; if (end > e) end = e;
    int m = end - base;

    // phase 1: load edges to registers (coalesced, read ONCE) + count buckets
    int sv[EPT], tv[EPT]; float wv[EPT];
    #pragma unroll
    for (int k = 0; k < EPT; ++k) {
        int i = base + k * B2T + tid;
        bool ok = (i < end);
        sv[k] = ok ? __builtin_nontemporal_load(src + i) : 0;
        tv[k] = ok ? __builtin_nontemporal_load(dst + i) : 0;
        wv[k] = ok ? __builtin_nontemporal_load(ew + i) : 0.0f;
        if (ok) {
            atomicAdd(&cd[(unsigned)tv[k] >> BSH], 1u);
            atomicAdd(&cs[(unsigned)sv[k] >> BSH], 1u);
        }
    }
    __syncthreads();

    // phase 2: dual exclusive scan over MAXB entries (all 512 threads)
    unsigned vd = 0, vs = 0;
    if (tid < MAXB) { vd = cd[tid]; vs = cs[tid]; ld[tid] = vd; ls[tid] = vs; }
    __syncthreads();
    for (int off = 1; off < MAXB; off <<= 1) {
        unsigned td = 0, ts = 0;
        if (tid < MAXB && tid >= off) { td = ld[tid - off]; ts = ls[tid - off]; }
        __syncthreads();
        if (tid < MAXB) { ld[tid] += td; ls[tid] += ts; }
        __syncthreads();
    }
    if (tid < MAXB) {
        ld[tid] -= vd; ls[tid] -= vs;            // exclusive starts
        cd[tid] = ld[tid]; cs[tid] = ls[tid];    // cursors
        if (tid < nbuk) {
            gbd[tid] = msc[tid * nblk + wb];
            gbs[tid] = msc[(nbuk + tid) * nblk + wb] - e;
        }
    }
    __syncthreads();

    // phase 3: place records from registers into LDS staging
    #pragma unroll
    for (int k = 0; k < EPT; ++k) {
        int i = base + k * B2T + tid;
        if (i < end) {
            float w = wv[k]; int s = sv[k]; int t = tv[k];
            unsigned wfix = (unsigned)(w * FIXS + 0.5f);
            if (wfix > 0x7FFFFFu) wfix = 0x7FFFFFu;
            unsigned tb = (unsigned)t >> BSH, sb = (unsigned)s >> BSH;
            unsigned pd = atomicAdd(&cd[tb], 1u);
            sd[pd] = ((u64)__float_as_uint(w) << 32)
                   | ((unsigned)s << BSH) | (unsigned)(t & BMSK);
            bdd[pd] = (unsigned short)tb;
            unsigned ps = atomicAdd(&cs[sb], 1u);
            ss[ps] = (wfix << BSH) | (unsigned)(s & BMSK);
            bds[ps] = (unsigned short)sb;
        }
    }
    __syncthreads();

    // phase 4: linear copy-out (coalesced within bucket runs)
    for (int p = tid; p < m; p += blockDim.x) {
        unsigned jd = bdd[p];
        bind[gbd[jd] + (int)(p - ld[jd])] = sd[p];
        unsigned js = bds[p];
        bins[gbs[js] + (int)(p - ls[js])] = ss[p];
    }
}

// ---- src weighted degrees per bucket -> iso ----
__global__ void k_srcdeg(const unsigned* __restrict__ bins, const int* __restrict__ msc,
                         float* __restrict__ iso, int n, int nblk, int nbuk, int e) {
    __shared__ unsigned wl[BKT];
    wl[threadIdx.x] = 0;
    __syncthreads();
    int b = blockIdx.x;
    int start = msc[(nbuk + b) * nblk] - e;
    int end = (b + 1 < nbuk) ? (msc[(nbuk + b + 1) * nblk] - e) : e;
    for (int i = start + threadIdx.x; i < end; i += blockDim.x) {
        unsigned r = bins[i];
        atomicAdd(&wl[r & BMSK], r >> BSH);
    }
    __syncthreads();
    int node = b * BKT + threadIdx.x;
    if (node < n)
        iso[node] = rsqrtf(1.0f + (float)wl[threadIdx.x] * INV_FIXS);
}

// ---- merged: dst histogram + isi + local rowptr scan + CSR fill ----
// pe staged in LDS at scanned positions -> coalesced copy-out.
__global__ void k_dstfill(const u64* __restrict__ bind, const int* __restrict__ msc,
                          const float* __restrict__ iso, float* __restrict__ isi,
                          int* __restrict__ cnt, int* __restrict__ rowptr,
                          unsigned* __restrict__ pe, int n, int nblk, int nbuk, int e) {
    __shared__ unsigned pst[MAXRUN];             // 24 KB pe staging
    __shared__ unsigned cl[BKT], wl[BKT], cur[BKT];
    __shared__ int sc[BKT];
    __shared__ float isL[BKT];
    cl[threadIdx.x] = 0; wl[threadIdx.x] = 0;
    __syncthreads();
    int b = blockIdx.x;
    int start = msc[b * nblk];
    int end = (b + 1 < nbuk) ? msc[(b + 1) * nblk] : e;
    int run = end - start;
    bool fast = (run <= MAXRUN);

    // pass A: histogram cnt + weighted degree
    for (int i = start + threadIdx.x; i < end; i += blockDim.x) {
        u64 r = bind[i];
        unsigned loc = (unsigned)r & BMSK;
        float w = __uint_as_float((unsigned)(r >> 32));
        unsigned wfix = (unsigned)(w * FIXS + 0.5f);
        if (wfix > 0x7FFFFFu) wfix = 0x7FFFFFu;
        atomicAdd(&cl[loc], 1u);
        atomicAdd(&wl[loc], wfix);
    }
    __syncthreads();

    // block-local exclusive scan of cl -> local rowptr
    int myc = (int)cl[threadIdx.x];
    sc[threadIdx.x] = myc;
    __syncthreads();
    for (int off = 1; off < BKT; off <<= 1) {
        int t = (threadIdx.x >= (unsigned)off) ? sc[threadIdx.x - off] : 0;
        __syncthreads();
        sc[threadIdx.x] += t;
        __syncthreads();
    }
    int lex = sc[threadIdx.x] - myc;             // local exclusive prefix
    int lrp = start + lex;

    float myisi = rsqrtf(1.0f + (float)wl[threadIdx.x] * INV_FIXS);
    isL[threadIdx.x] = myisi;
    cur[threadIdx.x] = fast ? (unsigned)lex : (unsigned)lrp;

    int node = b * BKT + threadIdx.x;
    if (node < n) {
        isi[node] = myisi;
        cnt[node] = myc;
        rowptr[node] = lrp;
    }
    __syncthreads();

    // pass B: build pe records (bind re-read is L2-hot)
    if (fast) {
        for (int i = start + threadIdx.x; i < end; i += blockDim.x) {
            u64 r = bind[i];
            unsigned lo = (unsigned)r;
            unsigned tloc = lo & BMSK;
            unsigned s = lo >> BSH;
            float w = __uint_as_float((unsigned)(r >> 32));
            float wv = w * iso[s] * isL[tloc];
            unsigned wq = (unsigned)(wv * WSC + 0.5f);
            if (wq > 32767u) wq = 32767u;
            unsigned pos = atomicAdd(&cur[tloc], 1u);
            pst[pos] = (s << 15) | wq;           // LDS scatter
        }
        __syncthreads();
        for (int p = threadIdx.x; p < run; p += blockDim.x)
            pe[start + p] = pst[p];              // coalesced copy-out
    } else {
        for (int i = start + threadIdx.x; i < end; i += blockDim.x) {
            u64 r = bind[i];
            unsigned lo = (unsigned)r;
            unsigned tloc = lo & BMSK;
            unsigned s = lo >> BSH;
            float w = __uint_as_float((unsigned)(r >> 32));
            float wv = w * iso[s] * isL[tloc];
            unsigned wq = (unsigned)(wv * WSC + 0.5f);
            if (wq > 32767u) wq = 32767u;
            unsigned pos = atomicAdd(&cur[tloc], 1u);
            pe[pos] = (s << 15) | wq;
        }
    }
}

// ---- one edge's FMA into the 8 accumulators ----
__device__ __forceinline__ void acc_edge(const uint4& u, float w,
                                         float& a0, float& a1, float& a2, float& a3,
                                         float& a4, float& a5, float& a6, float& a7) {
    const __half2* hp = (const __half2*)&u;
    float2 f0 = __half22float2(hp[0]);
    float2 f1 = __half22float2(hp[1]);
    float2 f2 = __half22float2(hp[2]);
    float2 f3 = __half22float2(hp[3]);
    a0 = fmaf(w, f0.x, a0); a1 = fmaf(w, f0.y, a1);
    a2 = fmaf(w, f1.x, a2); a3 = fmaf(w, f1.y, a3);
    a4 = fmaf(w, f2.x, a4); a5 = fmaf(w, f2.y, a5);
    a6 = fmaf(w, f3.x, a6); a7 = fmaf(w, f3.y, a7);
}

// chunk-7 (cols 56-63) is provably all-zero every iteration: skip its gather
__device__ __forceinline__ uint4 gld(const __half* p, bool en) {
    uint4 z; z.x = 0; z.y = 0; z.z = 0; z.w = 0;
    return en ? *(const uint4*)p : z;
}

// ---- fused iteration: 8 nodes/wave, 8 lanes/node, 8-edge-deep gather pipeline ----
__global__ void k_iter(const int* __restrict__ rowptr, const int* __restrict__ cnt,
                       const unsigned* __restrict__ pe, const __half* __restrict__ xin,
                       const __half* __restrict__ xpF, const float* __restrict__ iso,
                       const float* __restrict__ isi, __half* __restrict__ hout,
                       float* __restrict__ fout, int n, int final_iter) {
    int lane = threadIdx.x & 63;
    int c    = lane & 7;             // feature chunk 0..7 within group
    bool en  = (c < 7);              // chunk 7 is pure padding
    int waveId = (blockIdx.x * blockDim.x + threadIdx.x) >> 6;
    int node = waveId * 8 + (lane >> 3);
    if (node >= n) return;

    float a0 = 0.f, a1 = 0.f, a2 = 0.f, a3 = 0.f;
    float a4 = 0.f, a5 = 0.f, a6 = 0.f, a7 = 0.f;

    int beg = rowptr[node], m = cnt[node];

    int j = 0;
    for (; j + 8 <= m; j += 8) {
        unsigned p0 = pe[beg + j];
        unsigned p1 = pe[beg + j + 1];
        unsigned p2 = pe[beg + j + 2];
        unsigned p3 = pe[beg + j + 3];
        unsigned p4 = pe[beg + j + 4];
        unsigned p5 = pe[beg + j + 5];
        unsigned p6 = pe[beg + j + 6];
        unsigned p7 = pe[beg + j + 7];
        unsigned s0 = p0 >> 15; float w0 = (float)(p0 & 32767u) * INV_WSC;
        unsigned s1 = p1 >> 15; float w1 = (float)(p1 & 32767u) * INV_WSC;
        unsigned s2 = p2 >> 15; float w2 = (float)(p2 & 32767u) * INV_WSC;
        unsigned s3 = p3 >> 15; float w3 = (float)(p3 & 32767u) * INV_WSC;
        unsigned s4 = p4 >> 15; float w4 = (float)(p4 & 32767u) * INV_WSC;
        unsigned s5 = p5 >> 15; float w5 = (float)(p5 & 32767u) * INV_WSC;
        unsigned s6 = p6 >> 15; float w6 = (float)(p6 & 32767u) * INV_WSC;
        unsigned s7 = p7 >> 15; float w7 = (float)(p7 & 32767u) * INV_WSC;
        uint4 u0 = gld(xin + ((size_t)s0 << 6) + (c << 3), en);
        uint4 u1 = gld(xin + ((size_t)s1 << 6) + (c << 3), en);
        uint4 u2 = gld(xin + ((size_t)s2 << 6) + (c << 3), en);
        uint4 u3 = gld(xin + ((size_t)s3 << 6) + (c << 3), en);
        uint4 u4 = gld(xin + ((size_t)s4 << 6) + (c << 3), en);
        uint4 u5 = gld(xin + ((size_t)s5 << 6) + (c << 3), en);
        uint4 u6 = gld(xin + ((size_t)s6 << 6) + (c << 3), en);
        uint4 u7 = gld(xin + ((size_t)s7 << 6) + (c << 3), en);
        acc_edge(u0, w0, a0, a1, a2, a3, a4, a5, a6, a7);
        acc_edge(u1, w1, a0, a1, a2, a3, a4, a5, a6, a7);
        acc_edge(u2, w2, a0, a1, a2, a3, a4, a5, a6, a7);
        acc_edge(u3, w3, a0, a1, a2, a3, a4, a5, a6, a7);
        acc_edge(u4, w4, a0, a1, a2, a3, a4, a5, a6, a7);
        acc_edge(u5, w5, a0, a1, a2, a3, a4, a5, a6, a7);
        acc_edge(u6, w6, a0, a1, a2, a3, a4, a5, a6, a7);
        acc_edge(u7, w7, a0, a1, a2, a3, a4, a5, a6, a7);
    }
    for (; j + 4 <= m; j += 4) {
        unsigned p0 = pe[beg + j];
        unsigned p1 = pe[beg + j + 1];
        unsigned p2 = pe[beg + j + 2];
        unsigned p3 = pe[beg + j + 3];
        unsigned s0 = p0 >> 15; float w0 = (float)(p0 & 32767u) * INV_WSC;
        unsigned s1 = p1 >> 15; float w1 = (float)(p1 & 32767u) * INV_WSC;
        unsigned s2 = p2 >> 15; float w2 = (float)(p2 & 32767u) * INV_WSC;
        unsigned s3 = p3 >> 15; float w3 = (float)(p3 & 32767u) * INV_WSC;
        uint4 u0 = gld(xin + ((size_t)s0 << 6) + (c << 3), en);
        uint4 u1 = gld(xin + ((size_t)s1 << 6) + (c << 3), en);
        uint4 u2 = gld(xin + ((size_t)s2 << 6) + (c << 3), en);
        uint4 u3 = gld(xin + ((size_t)s3 << 6) + (c << 3), en);
        acc_edge(u0, w0, a0, a1, a2, a3, a4, a5, a6, a7);
        acc_edge(u1, w1, a0, a1, a2, a3, a4, a5, a6, a7);
        acc_edge(u2, w2, a0, a1, a2, a3, a4, a5, a6, a7);
        acc_edge(u3, w3, a0, a1, a2, a3, a4, a5, a6, a7);
    }
    for (; j < m; ++j) {
        unsigned p0 = pe[beg + j];
        unsigned s0 = p0 >> 15;
        float    w0 = (float)(p0 & 32767u) * INV_WSC;
        uint4 u0 = gld(xin + ((size_t)s0 << 6) + (c << 3), en);
        acc_edge(u0, w0, a0, a1, a2, a3, a4, a5, a6, a7);
    }

    // self-loop
    float selfw = iso[node] * isi[node];
    {
        uint4 u = gld(xin + ((size_t)node << 6) + (c << 3), en);
        acc_edge(u, selfw, a0, a1, a2, a3, a4, a5, a6, a7);
    }

    // feat from padded fp16 copy (pad cols are zero -> d=0 there)
    float f[8];
    {
        uint4 u = gld(xpF + ((size_t)node << 6) + (c << 3), en);
        const __half2* hp = (const __half2*)&u;
        float2 f0 = __half22float2(hp[0]);
        float2 f1 = __half22float2(hp[1]);
        float2 f2 = __half22float2(hp[2]);
        float2 f3 = __half22float2(hp[3]);
        f[0] = f0.x; f[1] = f0.y; f[2] = f1.x; f[3] = f1.y;
        f[4] = f2.x; f[5] = f2.y; f[6] = f3.x; f[7] = f3.y;
    }

    float d0 = a0 - f[0], d1 = a1 - f[1], d2 = a2 - f[2], d3 = a3 - f[3];
    float d4 = a4 - f[4], d5 = a5 - f[5], d6 = a6 - f[6], d7 = a7 - f[7];

    float ssum = d0*d0 + d1*d1 + d2*d2 + d3*d3 + d4*d4 + d5*d5 + d6*d6 + d7*d7;
    ssum += __shfl_xor(ssum, 1, 64);     // stays within the 8-lane group
    ssum += __shfl_xor(ssum, 2, 64);
    ssum += __shfl_xor(ssum, 4, 64);
    float norm = sqrtf(ssum);
    float sc = (norm > 0.0f) ? fmaxf(norm - GLAM, 0.0f) / norm : 0.0f;

    float o0 = f[0] + sc * d0, o1 = f[1] + sc * d1;
    float o2 = f[2] + sc * d2, o3 = f[3] + sc * d3;
    float o4 = f[4] + sc * d4, o5 = f[5] + sc * d5;
    float o6 = f[6] + sc * d6, o7 = f[7] + sc * d7;
    if (!final_iter) {
        if (en) {
            __half2 h0 = __float22half2_rn(make_float2(o0, o1));
            __half2 h1 = __float22half2_rn(make_float2(o2, o3));
            __half2 h2 = __float22half2_rn(make_float2(o4, o5));
            __half2 h3 = __float22half2_rn(make_float2(o6, o7));
            uint4 u;
            u.x = *(unsigned*)&h0; u.y = *(unsigned*)&h1;
            u.z = *(unsigned*)&h2; u.w = *(unsigned*)&h3;
            *(uint4*)(hout + ((size_t)node << 6) + (c << 3)) = u;
        }
    } else {
        float o[8] = {o0, o1, o2, o3, o4, o5, o6, o7};
        int fb = c << 3;
        #pragma unroll
        for (int k = 0; k < 4; ++k) {
            int ff = fb + (k << 1);
            if (ff + 1 < D) {
                float2 v; v.x = o[k * 2]; v.y = o[k * 2 + 1];
                *(float2*)(fout + (size_t)node * D + ff) = v;
            }
        }
    }
}

extern "C" void kernel_launch(void* const* d_in, const int* in_sizes, int n_in,
                              void* d_out, int out_size, void* d_ws, size_t ws_size,
                              hipStream_t stream) {
    const float* feat = (const float*)d_in[0];
    const float* ew   = (const float*)d_in[1];
    const int* src = (const int*)d_in[2];
    const int* dst = (const int*)d_in[3];

    const int nd = in_sizes[0];      // N * D
    const int n  = nd / D;           // N nodes
    const int e  = in_sizes[1];      // E edges
    const int np = n * PADH;         // padded fp16 element count

    const int nbuk = (n + BKT - 1) / BKT;       // 256-node buckets (391 @100k)
    const int nblk = (e + EPB - 1) / EPB;       // binning blocks (391 @1.6M)
    const int nm   = 2 * nbuk * nblk;           // count-matrix entries

    // workspace layout: 128B-aligned fp16 buffers first
    __half*   xpF    = (__half*)d_ws;           // np (fp16 feat, persistent)
    __half*   xpA    = xpF + np;                // np
    __half*   xpB    = xpA + np;                // np
    u64*      bind   = (u64*)(xpB + np);        // e   (dst-binned records)
    unsigned* pe     = (unsigned*)(bind + e);   // e   (final CSR: u32 s|w)
    unsigned* bins   = pe + e;                  // e   (src-binned records)
    int*      mat    = (int*)(bins + e);        // nm
    int*      msc    = mat + nm;                // nm
    float*    isi    = (float*)(msc + nm);      // n
    float*    iso    = isi + n;                 // n
    int*      cnt    = (int*)(iso + n);         // n
    int*      rowptr = cnt + n;                 // n
    int*      bsum   = rowptr + n;              // 1024
    float*    out    = (float*)d_out;

    const int B = 256;
    const int gP  = (np + B2T - 1) / B2T;       // pad blocks (fused into b1)
    const int NBm = (nm + SCAN_B - 1) / SCAN_B;

    k_b1p<<<nblk + gP, B2T, 0, stream>>>(src, dst, mat, feat, xpF, e, nblk, nbuk, n);
    k_scan1<<<NBm, SCAN_B, 0, stream>>>(mat, msc, bsum, nm);
    k_scan2<<<1, SCAN_B, 0, stream>>>(bsum, NBm);
    k_scan3<<<NBm, SCAN_B, 0, stream>>>(msc, bsum, nm);
    k_b2<<<nblk, B2T, 0, stream>>>(ew, src, dst, msc, bind, bins, e, nblk, nbuk);
    k_srcdeg<<<nbuk, BKT, 0, stream>>>(bins, msc, iso, n, nblk, nbuk, e);
    k_dstfill<<<nbuk, BKT, 0, stream>>>(bind, msc, iso, isi, cnt, rowptr, pe, n, nblk, nbuk, e);

    // 8 nodes per wave, 4 waves per block -> 32 nodes per block
    const int nodesPerBlock = (B / 64) * 8;
    const int iterGrid = (n + nodesPerBlock - 1) / nodesPerBlock;

    // iter1: xpF -> xpA ; iter2: xpA -> xpB ; iter3: xpB -> d_out (fp32)
    k_iter<<<iterGrid, B, 0, stream>>>(rowptr, cnt, pe, xpF, xpF, iso, isi, xpA, out, n, 0);
    k_iter<<<iterGrid, B, 0, stream>>>(rowptr, cnt, pe, xpA, xpF, iso, isi, xpB, out, n, 0);
    k_iter<<<iterGrid, B, 0, stream>>>(rowptr, cnt, pe, xpB, xpF, iso, isi, xpA, out, n, 1);
}

// Round 7
// 237.073 us; speedup vs baseline: 1.3943x; 1.3943x over previous
//
#include <hip/hip_runtime.h>
#include <hip/hip_bf16.h>
#include <hip/hip_fp16.h>

#define D 50
#define PADH 64                     // fp16 row stride: 128 B = 2 aligned 64B lines
#define GLAM 0.05555555555555555f   // gamma * lambda = (1/(2*0.9)) * 0.1
#define SCAN_B 1024
#define FIXS 8388608.0f             // 2^23 fixed-point scale (degree sums)
#define INV_FIXS (1.0f / 8388608.0f)
#define WSC 32768.0f                // 2^15 weight scale for u32 CSR records
#define INV_WSC (1.0f / 32768.0f)
#define EPB 4096                    // edges per binning block (62KB LDS -> 2 blocks/CU)
#define EPT 8                       // edges per thread in k_b2 (EPB/B2T)
#define B2T 512                     // threads for b1/b2
#define BSH 9                       // 512-node buckets
#define BMSK 511u
#define BT 512                      // threads for srcdeg/dstfill (= bucket size)
#define MAXB 256                    // max buckets (supports n <= 131072)
#define MAXRUN 12288                // pe staging capacity in k_dstfill (48 KB)
#define NXCD 8

typedef unsigned long long u64;

// ---- pass 1: per-block bucket histograms (dst+src), FUSED with feat->fp16 pad ----
__global__ void k_b1p(const int* __restrict__ src, const int* __restrict__ dst,
                      int* __restrict__ mat, const float* __restrict__ feat,
                      __half* __restrict__ xp, int e, int nblk, int nbuk, int n) {
    if ((int)blockIdx.x < nblk) {
        __shared__ unsigned hd[MAXB], hs[MAXB];
        for (int j = threadIdx.x; j < nbuk; j += blockDim.x) { hd[j] = 0; hs[j] = 0; }
        __syncthreads();
        int base = blockIdx.x * EPB;
        int end = base + EPB; if (end > e) end = e;
        for (int i = base + threadIdx.x; i < end; i += blockDim.x) {
            int t = __builtin_nontemporal_load(dst + i);
            int s = __builtin_nontemporal_load(src + i);
            atomicAdd(&hd[t >> BSH], 1u);
            atomicAdd(&hs[s >> BSH], 1u);
        }
        __syncthreads();
        for (int j = threadIdx.x; j < nbuk; j += blockDim.x) {
            mat[j * nblk + blockIdx.x] = (int)hd[j];
            mat[(nbuk + j) * nblk + blockIdx.x] = (int)hs[j];
        }
    } else {
        int i = ((int)blockIdx.x - nblk) * (int)blockDim.x + (int)threadIdx.x;
        if (i < n * PADH) {
            int node = i >> 6, col = i & 63;
            xp[i] = (col < D) ? __float2half_rn(feat[node * D + col]) : __half(0.0f);
        }
    }
}

// ---- 3-kernel exclusive scan (for the bucket-count matrix) ----
__global__ void k_scan1(const int* __restrict__ cnt, int* __restrict__ out,
                        int* __restrict__ bsum, int n) {
    __shared__ int s[SCAN_B];
    int i = blockIdx.x * SCAN_B + threadIdx.x;
    int v = (i < n) ? cnt[i] : 0;
    s[threadIdx.x] = v; __syncthreads();
    for (int off = 1; off < SCAN_B; off <<= 1) {
        int t = (threadIdx.x >= (unsigned)off) ? s[threadIdx.x - off] : 0;
        __syncthreads();
        s[threadIdx.x] += t; __syncthreads();
    }
    if (i < n) out[i] = s[threadIdx.x] - v;             // exclusive
    if (threadIdx.x == SCAN_B - 1) bsum[blockIdx.x] = s[threadIdx.x];
}

__global__ void k_scan2(int* __restrict__ bsum, int nb) {
    __shared__ int s[SCAN_B];
    int v = (threadIdx.x < (unsigned)nb) ? bsum[threadIdx.x] : 0;
    s[threadIdx.x] = v; __syncthreads();
    for (int off = 1; off < SCAN_B; off <<= 1) {
        int t = (threadIdx.x >= (unsigned)off) ? s[threadIdx.x - off] : 0;
        __syncthreads();
        s[threadIdx.x] += t; __syncthreads();
    }
    if (threadIdx.x < (unsigned)nb) bsum[threadIdx.x] = s[threadIdx.x] - v;  // exclusive
}

__global__ void k_scan3(int* __restrict__ out, const int* __restrict__ bsum, int n) {
    int i = blockIdx.x * SCAN_B + threadIdx.x;
    if (i < n) out[i] += bsum[blockIdx.x];
}

// ---- bijective chunked XCD swizzle (m204): phys block -> work block ----
__device__ __forceinline__ int xcd_swz(int p, int nwg) {
    int q = nwg / NXCD, r = nwg % NXCD;
    int xcd = p % NXCD, idx = p / NXCD;
    return (xcd < r ? xcd * (q + 1) : r * (q + 1) + (xcd - r) * q) + idx;
}

// ---- pass 2: LDS counting sort per block -> coalesced binned writes ----
// Edges held in registers (single HBM read). LDS ~62 KB -> 2 blocks/CU.
// Ordered placement (matrix scan) + XCD swizzle keeps adjacent chunks on
// the same XCD L2 so boundary partial lines merge.
__global__ __launch_bounds__(B2T, 4) void k_b2(
                     const float* __restrict__ ew, const int* __restrict__ src,
                     const int* __restrict__ dst, const int* __restrict__ msc,
                     u64* __restrict__ bind, unsigned* __restrict__ bins,
                     int e, int nblk, int nbuk) {
    __shared__ unsigned cd[MAXB], cs[MAXB];      // counts -> cursors
    __shared__ unsigned ld[MAXB], ls[MAXB];      // local exclusive starts
    __shared__ int gbd[MAXB], gbs[MAXB];         // global bases per bucket
    __shared__ u64 sd[EPB];                      // 32 KB dst-records staging
    __shared__ unsigned ss[EPB];                 // 16 KB src-records staging
    __shared__ unsigned char bdd[EPB], bds[EPB]; // bucket id per staged slot
    int tid = threadIdx.x;
    int wb = xcd_swz((int)blockIdx.x, nblk);
    if (tid < MAXB) { cd[tid] = 0; cs[tid] = 0; }
    __syncthreads();
    int base = wb * EPB;
    int end = base + EPB; if (end > e) end = e;
    int m = end - base;

    // phase 1: load edges to registers (coalesced, read ONCE) + count buckets
    int sv[EPT], tv[EPT]; float wv[EPT];
    #pragma unroll
    for (int k = 0; k < EPT; ++k) {
        int i = base + k * B2T + tid;
        bool ok = (i < end);
        sv[k] = ok ? __builtin_nontemporal_load(src + i) : 0;
        tv[k] = ok ? __builtin_nontemporal_load(dst + i) : 0;
        wv[k] = ok ? __builtin_nontemporal_load(ew + i) : 0.0f;
        if (ok) {
            atomicAdd(&cd[(unsigned)tv[k] >> BSH], 1u);
            atomicAdd(&cs[(unsigned)sv[k] >> BSH], 1u);
        }
    }
    __syncthreads();

    // phase 2: dual exclusive scan over MAXB entries (first 256 threads)
    unsigned vd = 0, vs = 0;
    if (tid < MAXB) { vd = cd[tid]; vs = cs[tid]; ld[tid] = vd; ls[tid] = vs; }
    __syncthreads();
    for (int off = 1; off < MAXB; off <<= 1) {
        unsigned td = 0, ts = 0;
        if (tid < MAXB && tid >= off) { td = ld[tid - off]; ts = ls[tid - off]; }
        __syncthreads();
        if (tid < MAXB) { ld[tid] += td; ls[tid] += ts; }
        __syncthreads();
    }
    if (tid < MAXB) {
        ld[tid] -= vd; ls[tid] -= vs;            // exclusive starts
        cd[tid] = ld[tid]; cs[tid] = ls[tid];    // cursors
        if (tid < nbuk) {
            gbd[tid] = msc[tid * nblk + wb];
            gbs[tid] = msc[(nbuk + tid) * nblk + wb] - e;
        }
    }
    __syncthreads();

    // phase 3: place records from registers into LDS staging
    #pragma unroll
    for (int k = 0; k < EPT; ++k) {
        int i = base + k * B2T + tid;
        if (i < end) {
            float w = wv[k]; int s = sv[k]; int t = tv[k];
            unsigned wfix = (unsigned)(w * FIXS + 0.5f);
            if (wfix > 0x7FFFFFu) wfix = 0x7FFFFFu;
            unsigned tb = (unsigned)t >> BSH, sb = (unsigned)s >> BSH;
            unsigned pd = atomicAdd(&cd[tb], 1u);
            sd[pd] = ((u64)__float_as_uint(w) << 32)
                   | ((unsigned)s << BSH) | (unsigned)(t & BMSK);
            bdd[pd] = (unsigned char)tb;
            unsigned ps = atomicAdd(&cs[sb], 1u);
            ss[ps] = (wfix << BSH) | (unsigned)(s & BMSK);
            bds[ps] = (unsigned char)sb;
        }
    }
    __syncthreads();

    // phase 4: linear copy-out (coalesced within bucket runs)
    for (int p = tid; p < m; p += blockDim.x) {
        unsigned jd = bdd[p];
        bind[gbd[jd] + (int)(p - ld[jd])] = sd[p];
        unsigned js = bds[p];
        bins[gbs[js] + (int)(p - ls[js])] = ss[p];
    }
}

// ---- src weighted degrees per bucket -> iso ----
__global__ void k_srcdeg(const unsigned* __restrict__ bins, const int* __restrict__ msc,
                         float* __restrict__ iso, int n, int nblk, int nbuk, int e) {
    __shared__ unsigned wl[BT];
    wl[threadIdx.x] = 0;
    __syncthreads();
    int b = blockIdx.x;
    int start = msc[(nbuk + b) * nblk] - e;
    int end = (b + 1 < nbuk) ? (msc[(nbuk + b + 1) * nblk] - e) : e;
    for (int i = start + threadIdx.x; i < end; i += blockDim.x) {
        unsigned r = bins[i];
        atomicAdd(&wl[r & BMSK], r >> BSH);
    }
    __syncthreads();
    int node = b * BT + threadIdx.x;
    if (node < n)
        iso[node] = rsqrtf(1.0f + (float)wl[threadIdx.x] * INV_FIXS);
}

// ---- merged: dst histogram + isi + local rowptr scan + CSR fill ----
// pe records staged in LDS at locally-scanned positions, then coalesced
// copy-out: no address-divergent global stores. LDS ~58 KB -> 2 blocks/CU.
__global__ void k_dstfill(const u64* __restrict__ bind, const int* __restrict__ msc,
                          const float* __restrict__ iso, float* __restrict__ isi,
                          int* __restrict__ cnt, int* __restrict__ rowptr,
                          unsigned* __restrict__ pe, int n, int nblk, int nbuk, int e) {
    __shared__ unsigned pst[MAXRUN];             // 48 KB pe staging
    __shared__ unsigned cl[BT], wl[BT], cur[BT];
    __shared__ int sc[BT];
    __shared__ float isL[BT];
    cl[threadIdx.x] = 0; wl[threadIdx.x] = 0;
    __syncthreads();
    int b = blockIdx.x;
    int start = msc[b * nblk];
    int end = (b + 1 < nbuk) ? msc[(b + 1) * nblk] : e;
    int run = end - start;
    bool fast = (run <= MAXRUN);

    // pass A: histogram cnt + weighted degree (bind read warms L2)
    for (int i = start + threadIdx.x; i < end; i += blockDim.x) {
        u64 r = bind[i];
        unsigned loc = (unsigned)r & BMSK;
        float w = __uint_as_float((unsigned)(r >> 32));
        unsigned wfix = (unsigned)(w * FIXS + 0.5f);
        if (wfix > 0x7FFFFFu) wfix = 0x7FFFFFu;
        atomicAdd(&cl[loc], 1u);
        atomicAdd(&wl[loc], wfix);
    }
    __syncthreads();

    // block-local exclusive scan of cl -> local rowptr
    int myc = (int)cl[threadIdx.x];
    sc[threadIdx.x] = myc;
    __syncthreads();
    for (int off = 1; off < BT; off <<= 1) {
        int t = (threadIdx.x >= (unsigned)off) ? sc[threadIdx.x - off] : 0;
        __syncthreads();
        sc[threadIdx.x] += t;
        __syncthreads();
    }
    int lex = sc[threadIdx.x] - myc;             // local exclusive prefix
    int lrp = start + lex;

    float myisi = rsqrtf(1.0f + (float)wl[threadIdx.x] * INV_FIXS);
    isL[threadIdx.x] = myisi;
    cur[threadIdx.x] = fast ? (unsigned)lex : (unsigned)lrp;

    int node = b * BT + threadIdx.x;
    if (node < n) {
        isi[node] = myisi;
        cnt[node] = myc;
        rowptr[node] = lrp;
    }
    __syncthreads();

    // pass B: build pe records (bind re-read is L2-hot)
    if (fast) {
        for (int i = start + threadIdx.x; i < end; i += blockDim.x) {
            u64 r = bind[i];
            unsigned lo = (unsigned)r;
            unsigned tloc = lo & BMSK;
            unsigned s = lo >> BSH;
            float w = __uint_as_float((unsigned)(r >> 32));
            float wv = w * iso[s] * isL[tloc];
            unsigned wq = (unsigned)(wv * WSC + 0.5f);
            if (wq > 32767u) wq = 32767u;
            unsigned pos = atomicAdd(&cur[tloc], 1u);
            pst[pos] = (s << 15) | wq;           // LDS scatter (bank-granular)
        }
        __syncthreads();
        // coalesced copy-out
        for (int p = threadIdx.x; p < run; p += blockDim.x)
            pe[start + p] = pst[p];
    } else {
        for (int i = start + threadIdx.x; i < end; i += blockDim.x) {
            u64 r = bind[i];
            unsigned lo = (unsigned)r;
            unsigned tloc = lo & BMSK;
            unsigned s = lo >> BSH;
            float w = __uint_as_float((unsigned)(r >> 32));
            float wv = w * iso[s] * isL[tloc];
            unsigned wq = (unsigned)(wv * WSC + 0.5f);
            if (wq > 32767u) wq = 32767u;
            unsigned pos = atomicAdd(&cur[tloc], 1u);
            pe[pos] = (s << 15) | wq;
        }
    }
}

// ---- one edge's FMA into the 8 accumulators ----
__device__ __forceinline__ void acc_edge(const uint4& u, float w,
                                         float& a0, float& a1, float& a2, float& a3,
                                         float& a4, float& a5, float& a6, float& a7) {
    const __half2* hp = (const __half2*)&u;
    float2 f0 = __half22float2(hp[0]);
    float2 f1 = __half22float2(hp[1]);
    float2 f2 = __half22float2(hp[2]);
    float2 f3 = __half22float2(hp[3]);
    a0 = fmaf(w, f0.x, a0); a1 = fmaf(w, f0.y, a1);
    a2 = fmaf(w, f1.x, a2); a3 = fmaf(w, f1.y, a3);
    a4 = fmaf(w, f2.x, a4); a5 = fmaf(w, f2.y, a5);
    a6 = fmaf(w, f3.x, a6); a7 = fmaf(w, f3.y, a7);
}

// ---- fused iteration: 8 nodes/wave, 8 lanes/node, 8-edge-deep gather pipeline ----
__global__ void k_iter(const int* __restrict__ rowptr, const int* __restrict__ cnt,
                       const unsigned* __restrict__ pe, const __half* __restrict__ xin,
                       const __half* __restrict__ xpF, const float* __restrict__ iso,
                       const float* __restrict__ isi, __half* __restrict__ hout,
                       float* __restrict__ fout, int n, int final_iter) {
    int lane = threadIdx.x & 63;
    int c    = lane & 7;             // feature chunk 0..7 within group
    int waveId = (blockIdx.x * blockDim.x + threadIdx.x) >> 6;
    int node = waveId * 8 + (lane >> 3);
    if (node >= n) return;

    float a0 = 0.f, a1 = 0.f, a2 = 0.f, a3 = 0.f;
    float a4 = 0.f, a5 = 0.f, a6 = 0.f, a7 = 0.f;

    int beg = rowptr[node], m = cnt[node];

    int j = 0;
    for (; j + 8 <= m; j += 8) {
        unsigned p0 = pe[beg + j];
        unsigned p1 = pe[beg + j + 1];
        unsigned p2 = pe[beg + j + 2];
        unsigned p3 = pe[beg + j + 3];
        unsigned p4 = pe[beg + j + 4];
        unsigned p5 = pe[beg + j + 5];
        unsigned p6 = pe[beg + j + 6];
        unsigned p7 = pe[beg + j + 7];
        unsigned s0 = p0 >> 15; float w0 = (float)(p0 & 32767u) * INV_WSC;
        unsigned s1 = p1 >> 15; float w1 = (float)(p1 & 32767u) * INV_WSC;
        unsigned s2 = p2 >> 15; float w2 = (float)(p2 & 32767u) * INV_WSC;
        unsigned s3 = p3 >> 15; float w3 = (float)(p3 & 32767u) * INV_WSC;
        unsigned s4 = p4 >> 15; float w4 = (float)(p4 & 32767u) * INV_WSC;
        unsigned s5 = p5 >> 15; float w5 = (float)(p5 & 32767u) * INV_WSC;
        unsigned s6 = p6 >> 15; float w6 = (float)(p6 & 32767u) * INV_WSC;
        unsigned s7 = p7 >> 15; float w7 = (float)(p7 & 32767u) * INV_WSC;
        uint4 u0 = *(const uint4*)(xin + ((size_t)s0 << 6) + (c << 3));
        uint4 u1 = *(const uint4*)(xin + ((size_t)s1 << 6) + (c << 3));
        uint4 u2 = *(const uint4*)(xin + ((size_t)s2 << 6) + (c << 3));
        uint4 u3 = *(const uint4*)(xin + ((size_t)s3 << 6) + (c << 3));
        uint4 u4 = *(const uint4*)(xin + ((size_t)s4 << 6) + (c << 3));
        uint4 u5 = *(const uint4*)(xin + ((size_t)s5 << 6) + (c << 3));
        uint4 u6 = *(const uint4*)(xin + ((size_t)s6 << 6) + (c << 3));
        uint4 u7 = *(const uint4*)(xin + ((size_t)s7 << 6) + (c << 3));
        acc_edge(u0, w0, a0, a1, a2, a3, a4, a5, a6, a7);
        acc_edge(u1, w1, a0, a1, a2, a3, a4, a5, a6, a7);
        acc_edge(u2, w2, a0, a1, a2, a3, a4, a5, a6, a7);
        acc_edge(u3, w3, a0, a1, a2, a3, a4, a5, a6, a7);
        acc_edge(u4, w4, a0, a1, a2, a3, a4, a5, a6, a7);
        acc_edge(u5, w5, a0, a1, a2, a3, a4, a5, a6, a7);
        acc_edge(u6, w6, a0, a1, a2, a3, a4, a5, a6, a7);
        acc_edge(u7, w7, a0, a1, a2, a3, a4, a5, a6, a7);
    }
    for (; j + 4 <= m; j += 4) {
        unsigned p0 = pe[beg + j];
        unsigned p1 = pe[beg + j + 1];
        unsigned p2 = pe[beg + j + 2];
        unsigned p3 = pe[beg + j + 3];
        unsigned s0 = p0 >> 15; float w0 = (float)(p0 & 32767u) * INV_WSC;
        unsigned s1 = p1 >> 15; float w1 = (float)(p1 & 32767u) * INV_WSC;
        unsigned s2 = p2 >> 15; float w2 = (float)(p2 & 32767u) * INV_WSC;
        unsigned s3 = p3 >> 15; float w3 = (float)(p3 & 32767u) * INV_WSC;
        uint4 u0 = *(const uint4*)(xin + ((size_t)s0 << 6) + (c << 3));
        uint4 u1 = *(const uint4*)(xin + ((size_t)s1 << 6) + (c << 3));
        uint4 u2 = *(const uint4*)(xin + ((size_t)s2 << 6) + (c << 3));
        uint4 u3 = *(const uint4*)(xin + ((size_t)s3 << 6) + (c << 3));
        acc_edge(u0, w0, a0, a1, a2, a3, a4, a5, a6, a7);
        acc_edge(u1, w1, a0, a1, a2, a3, a4, a5, a6, a7);
        acc_edge(u2, w2, a0, a1, a2, a3, a4, a5, a6, a7);
        acc_edge(u3, w3, a0, a1, a2, a3, a4, a5, a6, a7);
    }
    for (; j < m; ++j) {
        unsigned p0 = pe[beg + j];
        unsigned s0 = p0 >> 15;
        float    w0 = (float)(p0 & 32767u) * INV_WSC;
        uint4 u0 = *(const uint4*)(xin + ((size_t)s0 << 6) + (c << 3));
        acc_edge(u0, w0, a0, a1, a2, a3, a4, a5, a6, a7);
    }

    // self-loop
    float selfw = iso[node] * isi[node];
    {
        uint4 u = *(const uint4*)(xin + ((size_t)node << 6) + (c << 3));
        acc_edge(u, selfw, a0, a1, a2, a3, a4, a5, a6, a7);
    }

    // feat from padded fp16 copy (pad cols are zero -> d=0 there)
    float f[8];
    {
        uint4 u = *(const uint4*)(xpF + ((size_t)node << 6) + (c << 3));
        const __half2* hp = (const __half2*)&u;
        float2 f0 = __half22float2(hp[0]);
        float2 f1 = __half22float2(hp[1]);
        float2 f2 = __half22float2(hp[2]);
        float2 f3 = __half22float2(hp[3]);
        f[0] = f0.x; f[1] = f0.y; f[2] = f1.x; f[3] = f1.y;
        f[4] = f2.x; f[5] = f2.y; f[6] = f3.x; f[7] = f3.y;
    }

    float d0 = a0 - f[0], d1 = a1 - f[1], d2 = a2 - f[2], d3 = a3 - f[3];
    float d4 = a4 - f[4], d5 = a5 - f[5], d6 = a6 - f[6], d7 = a7 - f[7];

    float ssum = d0*d0 + d1*d1 + d2*d2 + d3*d3 + d4*d4 + d5*d5 + d6*d6 + d7*d7;
    ssum += __shfl_xor(ssum, 1, 64);     // stays within the 8-lane group
    ssum += __shfl_xor(ssum, 2, 64);
    ssum += __shfl_xor(ssum, 4, 64);
    float norm = sqrtf(ssum);
    float sc = (norm > 0.0f) ? fmaxf(norm - GLAM, 0.0f) / norm : 0.0f;

    float o0 = f[0] + sc * d0, o1 = f[1] + sc * d1;
    float o2 = f[2] + sc * d2, o3 = f[3] + sc * d3;
    float o4 = f[4] + sc * d4, o5 = f[5] + sc * d5;
    float o6 = f[6] + sc * d6, o7 = f[7] + sc * d7;
    if (!final_iter) {
        __half2 h0 = __float22half2_rn(make_float2(o0, o1));
        __half2 h1 = __float22half2_rn(make_float2(o2, o3));
        __half2 h2 = __float22half2_rn(make_float2(o4, o5));
        __half2 h3 = __float22half2_rn(make_float2(o6, o7));
        uint4 u;
        u.x = *(unsigned*)&h0; u.y = *(unsigned*)&h1;
        u.z = *(unsigned*)&h2; u.w = *(unsigned*)&h3;
        *(uint4*)(hout + ((size_t)node << 6) + (c << 3)) = u;
    } else {
        float o[8] = {o0, o1, o2, o3, o4, o5, o6, o7};
        int fb = c << 3;
        #pragma unroll
        for (int k = 0; k < 4; ++k) {
            int ff = fb + (k << 1);
            if (ff + 1 < D) {
                float2 v; v.x = o[k * 2]; v.y = o[k * 2 + 1];
                *(float2*)(fout + (size_t)node * D + ff) = v;
            }
        }
    }
}

extern "C" void kernel_launch(void* const* d_in, const int* in_sizes, int n_in,
                              void* d_out, int out_size, void* d_ws, size_t ws_size,
                              hipStream_t stream) {
    const float* feat = (const float*)d_in[0];
    const float* ew   = (const float*)d_in[1];
    const int* src = (const int*)d_in[2];
    const int* dst = (const int*)d_in[3];

    const int nd = in_sizes[0];      // N * D
    const int n  = nd / D;           // N nodes
    const int e  = in_sizes[1];      // E edges
    const int np = n * PADH;         // padded fp16 element count

    const int nbuk = (n + BT - 1) / BT;         // 512-node buckets (196 @100k)
    const int nblk = (e + EPB - 1) / EPB;       // binning blocks (391 @1.6M)
    const int nm   = 2 * nbuk * nblk;           // count-matrix entries

    // workspace layout: 128B-aligned fp16 buffers first
    __half*   xpF    = (__half*)d_ws;           // np (fp16 feat, persistent)
    __half*   xpA    = xpF + np;                // np
    __half*   xpB    = xpA + np;                // np
    u64*      bind   = (u64*)(xpB + np);        // e   (dst-binned records)
    unsigned* pe     = (unsigned*)(bind + e);   // e   (final CSR: u32 s|w)
    unsigned* bins   = pe + e;                  // e   (src-binned records)
    int*      mat    = (int*)(bins + e);        // nm
    int*      msc    = mat + nm;                // nm
    float*    isi    = (float*)(msc + nm);      // n
    float*    iso    = isi + n;                 // n
    int*      cnt    = (int*)(iso + n);         // n
    int*      rowptr = cnt + n;                 // n
    int*      bsum   = rowptr + n;              // 1024
    float*    out    = (float*)d_out;

    const int B = 256;
    const int gP  = (np + B2T - 1) / B2T;       // pad blocks (fused into b1)
    const int NBm = (nm + SCAN_B - 1) / SCAN_B;

    k_b1p<<<nblk + gP, B2T, 0, stream>>>(src, dst, mat, feat, xpF, e, nblk, nbuk, n);
    k_scan1<<<NBm, SCAN_B, 0, stream>>>(mat, msc, bsum, nm);
    k_scan2<<<1, SCAN_B, 0, stream>>>(bsum, NBm);
    k_scan3<<<NBm, SCAN_B, 0, stream>>>(msc, bsum, nm);
    k_b2<<<nblk, B2T, 0, stream>>>(ew, src, dst, msc, bind, bins, e, nblk, nbuk);
    k_srcdeg<<<nbuk, BT, 0, stream>>>(bins, msc, iso, n, nblk, nbuk, e);
    k_dstfill<<<nbuk, BT, 0, stream>>>(bind, msc, iso, isi, cnt, rowptr, pe, n, nblk, nbuk, e);

    // 8 nodes per wave, 4 waves per block -> 32 nodes per block
    const int nodesPerBlock = (B / 64) * 8;
    const int iterGrid = (n + nodesPerBlock - 1) / nodesPerBlock;

    // iter1: xpF -> xpA ; iter2: xpA -> xpB ; iter3: xpB -> d_out (fp32)
    k_iter<<<iterGrid, B, 0, stream>>>(rowptr, cnt, pe, xpF, xpF, iso, isi, xpA, out, n, 0);
    k_iter<<<iterGrid, B, 0, stream>>>(rowptr, cnt, pe, xpA, xpF, iso, isi, xpB, out, n, 0);
    k_iter<<<iterGrid, B, 0, stream>>>(rowptr, cnt, pe, xpB, xpF, iso, isi, xpA, out, n, 1);
}